// Round 1
// 153.873 us; speedup vs baseline: 1.0068x; 1.0068x over previous
//
#include <hip/hip_runtime.h>

// ROIAlign: features (B=4, C=64, H=38, W=38) fp32, rois (B=4, 2904, 4) fp32
// out: (N=11616, C=64, 7, 7) fp32
// R5: issue-count attack. half8 (16B) gathers (8 lanes/point, 2 passes),
// flat e-indexed LDS result tile (phase 3 = straight copy, no divisions),
// float4 nontemporal output stores (protect fhwc L2 residency),
// phase-1 spread over 196 threads (one per point-corner).
#define OUTSZ 7
#define PP    (OUTSZ * OUTSZ)   // 49 sample positions per ROI
#define NCH   64
#define FH    38
#define FW    38
#define NB    2904
#define HWSZ  (FH * FW)         // 1444
#define CHW   (NCH * HWSZ)      // 92416 per batch
#define ROI_ELEMS (NCH * PP)    // 3136 floats per ROI

typedef __attribute__((ext_vector_type(4))) _Float16 half4;
typedef __attribute__((ext_vector_type(8))) _Float16 half8;
typedef __attribute__((ext_vector_type(4))) float    float4v;

// --- Kernel A: CHW fp32 -> HWC fp16 transpose via LDS tile (32 pos x 64 ch) ---
__global__ __launch_bounds__(256) void transpose_kernel(
    const float* __restrict__ feat,   // (4,64,38,38) fp32
    _Float16* __restrict__ fhwc)      // (4,38,38,64) fp16
{
    __shared__ float s[64][33];
    const int b   = blockIdx.y;
    const int yx0 = blockIdx.x * 32;
    const int tid  = threadIdx.x;
    const int lane = tid & 31;
    const int grp  = tid >> 5;        // 0..7

    const int yx = yx0 + lane;
    if (yx < HWSZ) {
        #pragma unroll
        for (int i = 0; i < 8; ++i) {
            const int c = grp * 8 + i;
            s[c][lane] = feat[b * CHW + c * HWSZ + yx];   // coalesced along yx
        }
    }
    __syncthreads();
    // write: 512 items = 32 positions x 16 channel-quads, half4 (8B) stores
    #pragma unroll
    for (int it = 0; it < 2; ++it) {
        const int item = it * 256 + tid;       // 0..511
        const int q    = item & 15;            // channel quad 0..15
        const int yxl  = item >> 4;            // 0..31
        const int yxg  = yx0 + yxl;
        if (yxg < HWSZ) {
            half4 v;
            v[0] = (_Float16)s[q * 4 + 0][yxl];
            v[1] = (_Float16)s[q * 4 + 1][yxl];
            v[2] = (_Float16)s[q * 4 + 2][yxl];
            v[3] = (_Float16)s[q * 4 + 3][yxl];
            *reinterpret_cast<half4*>(fhwc + b * CHW + yxg * NCH + q * 4) = v;
        }
    }
}

// --- Kernel B: one block (256 thr = 4 waves) per ROI ---
__global__ __launch_bounds__(256, 8) void roi_align_kernel(
    const _Float16* __restrict__ fhwc,
    const float* __restrict__ rois,
    float* __restrict__ out)
{
    __shared__ float s_w[PP][4];
    __shared__ int   s_off[PP][4];      // element offsets into batch-HWC plane
    __shared__ float s_t[ROI_ELEMS];    // flat, e = c*49 + p  (output order)

    const int n   = blockIdx.x;         // roi index 0..11615
    const int b   = n / NB;
    const int tid = threadIdx.x;

    // Phase 1: 196 threads, one per (point, corner)
    if (tid < PP * 4) {
        const int p = tid >> 2;
        const int k = tid & 3;
        const float x1 = rois[n * 4 + 0];
        const float y1 = rois[n * 4 + 1];
        const float x2 = rois[n * 4 + 2];
        const float y2 = rois[n * 4 + 3];
        const float w = fmaxf(x2 - x1, 1.0f);
        const float h = fmaxf(y2 - y1, 1.0f);
        const int i = p / OUTSZ;
        const int j = p % OUTSZ;
        const float x = x1 + ((float)j * (1.0f / 6.0f)) * w;
        const float y = y1 + ((float)i * (1.0f / 6.0f)) * h;
        const float x0f = floorf(x);
        const float y0f = floorf(y);
        const float fx = x - x0f;
        const float fy = y - y0f;
        const int dx = k & 1;
        const int dy = k >> 1;
        const float wx = dx ? fx : 1.0f - fx;
        const float wy = dy ? fy : 1.0f - fy;
        const int xc = (int)x0f + dx;
        const int yc = (int)y0f + dy;
        const bool valid = (xc >= 0) && (xc <= FW - 1) && (yc >= 0) && (yc <= FH - 1);
        const int xi = min(max(xc, 0), FW - 1);
        const int yi = min(max(yc, 0), FH - 1);
        s_w[p][k]   = valid ? wx * wy : 0.0f;
        s_off[p][k] = (yi * FW + xi) * NCH;
    }
    __syncthreads();

    const _Float16* __restrict__ fb = fhwc + (size_t)b * CHW;

    // Phase 2: 8 lanes per sample point, each lane owns 8 consecutive channels.
    // half8 loads: 16 B/lane; one wave-load = 8 points x 128 B, fully coalesced.
    const int sub = tid & 7;            // channel octet index 0..7
    const int pg  = tid >> 3;           // point slot 0..31
    const int c0  = sub * 8;
    #pragma unroll
    for (int pass = 0; pass < 2; ++pass) {
        const int p = pass * 32 + pg;   // 0..63
        if (p < PP) {
            const float w0 = s_w[p][0], w1 = s_w[p][1], w2 = s_w[p][2], w3 = s_w[p][3];
            const half8 v0 = *reinterpret_cast<const half8*>(fb + s_off[p][0] + c0);
            const half8 v1 = *reinterpret_cast<const half8*>(fb + s_off[p][1] + c0);
            const half8 v2 = *reinterpret_cast<const half8*>(fb + s_off[p][2] + c0);
            const half8 v3 = *reinterpret_cast<const half8*>(fb + s_off[p][3] + c0);
            // LDS writes: bank = (8*sub + 17*c + p) mod 32 -> exactly 2-way (free)
            #pragma unroll
            for (int c = 0; c < 8; ++c) {
                s_t[(c0 + c) * PP + p] =
                    (float)v0[c] * w0 + (float)v1[c] * w1 +
                    (float)v2[c] * w2 + (float)v3[c] * w3;
            }
        }
    }
    __syncthreads();

    // Phase 3: straight flat copy, float4 nontemporal stores (784 vec4s).
    float* __restrict__ ob = out + (size_t)n * ROI_ELEMS;
    #pragma unroll
    for (int it = 0; it < 4; ++it) {
        const int idx = tid + it * 256;
        if (idx < ROI_ELEMS / 4) {
            const int e4 = idx * 4;
            float4v r;
            r[0] = s_t[e4 + 0];
            r[1] = s_t[e4 + 1];
            r[2] = s_t[e4 + 2];
            r[3] = s_t[e4 + 3];
            __builtin_nontemporal_store(r, reinterpret_cast<float4v*>(ob + e4));
        }
    }
}

extern "C" void kernel_launch(void* const* d_in, const int* in_sizes, int n_in,
                              void* d_out, int out_size, void* d_ws, size_t ws_size,
                              hipStream_t stream) {
    const float* feat = (const float*)d_in[0];   // 4*64*38*38
    const float* rois = (const float*)d_in[1];   // 4*2904*4
    float* out  = (float*)d_out;                 // 11616*64*7*7
    _Float16* fhwc = (_Float16*)d_ws;            // 4*38*38*64 fp16 = 739 KB scratch

    dim3 tg((HWSZ + 31) / 32, 4);
    transpose_kernel<<<tg, 256, 0, stream>>>(feat, fhwc);
    roi_align_kernel<<<4 * NB, 256, 0, stream>>>(fhwc, rois, out);
}